// Round 2
// baseline (55641.949 us; speedup 1.0000x reference)
//
#include <hip/hip_runtime.h>
#include <hip/hip_bf16.h>
#include <math.h>

#define N_WORDS 8192
#define LMAX    16
#define WED     506
#define WHD     512
#define CED     6
#define CHD     6
#define CVOC    128
#define TAG     64
#define XDIM    512      // WED + CHD
#define G4      2048     // 4*WHD

__device__ __forceinline__ float fast_sigmoid(float x) { return 1.0f / (1.0f + __expf(-x)); }
__device__ __forceinline__ float fast_tanh(float x)    { return 2.0f / (1.0f + __expf(-2.0f * x)) - 1.0f; }

// ---------------- Kernel A: char-level LSTM, one thread per word ----------------
__global__ void __launch_bounds__(256) char_lstm_kernel(
    const int*   __restrict__ chars,     // [N, LMAX]
    const int*   __restrict__ lens,      // [N]
    const float* __restrict__ char_emb,  // [CVOC, CED]
    const float* __restrict__ cWih,      // [24, 6]
    const float* __restrict__ cWhh,      // [24, 6]
    const float* __restrict__ cb,        // [24]
    float*       __restrict__ h_char)    // [N, CHD]
{
    __shared__ float sWih[24][6], sWhh[24][6], sb[24], semb[CVOC][CED];
    int t = threadIdx.x;
    if (t < 144) { sWih[t / 6][t % 6] = cWih[t]; sWhh[t / 6][t % 6] = cWhh[t]; }
    if (t < 24) sb[t] = cb[t];
    for (int i = t; i < CVOC * CED; i += 256) semb[i / CED][i % CED] = char_emb[i];
    __syncthreads();

    int n = blockIdx.x * 256 + t;
    if (n >= N_WORDS) return;
    int len = lens[n];
    float h[CHD] = {0, 0, 0, 0, 0, 0};
    float c[CHD] = {0, 0, 0, 0, 0, 0};
    for (int l = 0; l < LMAX; ++l) {
        if (l >= len) break;  // once l >= len no further state updates occur
        int ch = chars[n * LMAX + l];
        float e[CED];
        #pragma unroll
        for (int k = 0; k < CED; ++k) e[k] = semb[ch][k];
        float pre[24];
        #pragma unroll
        for (int g = 0; g < 24; ++g) {
            float a = sb[g];
            #pragma unroll
            for (int k = 0; k < CED; ++k) a += e[k] * sWih[g][k];
            #pragma unroll
            for (int k = 0; k < CHD; ++k) a += h[k] * sWhh[g][k];
            pre[g] = a;
        }
        #pragma unroll
        for (int u = 0; u < CHD; ++u) {
            float ig = fast_sigmoid(pre[u]);
            float fg = fast_sigmoid(pre[6 + u]);
            float gg = fast_tanh(pre[12 + u]);
            float og = fast_sigmoid(pre[18 + u]);
            float cn = fg * c[u] + ig * gg;
            c[u] = cn;
            h[u] = og * fast_tanh(cn);
        }
    }
    for (int u = 0; u < CHD; ++u) h_char[n * CHD + u] = h[u];
}

// ---------------- Kernel B0: X = [word_emb gather | h_char] ----------------
__global__ void __launch_bounds__(256) build_x_kernel(
    const int*   __restrict__ words,
    const float* __restrict__ word_emb,  // [WV, WED]
    const float* __restrict__ h_char,    // [N, CHD]
    float*       __restrict__ X)         // [N, XDIM]
{
    long idx = (long)blockIdx.x * 256 + threadIdx.x;
    if (idx >= (long)N_WORDS * XDIM) return;
    int n = (int)(idx >> 9), k = (int)(idx & 511);
    float v;
    if (k < WED) v = word_emb[(long)words[n] * WED + k];
    else         v = h_char[n * CHD + (k - WED)];
    X[idx] = v;
}

// ---------------- Kernel B1: XP4 = X @ Wih^T + b, fp32 tiled GEMM ----------------
// Epilogue writes gate-interleaved layout XP4[t][unit][gate] so the word LSTM
// reads one float4 per thread per step.
#define BM 64
#define BN 64
#define BK 16
__global__ void __launch_bounds__(256) xp_gemm_kernel(
    const float* __restrict__ X,    // [N, 512]
    const float* __restrict__ Wih,  // [2048, 512]
    const float* __restrict__ wb,   // [2048]
    float*       __restrict__ XP4)  // [N, 512, 4]
{
    __shared__ float As[BM][BK + 1];
    __shared__ float Bs[BN][BK + 1];
    int tid = threadIdx.x;
    int bm = (blockIdx.x % (N_WORDS / BM)) * BM;
    int bn = (blockIdx.x / (N_WORDS / BM)) * BN;
    int ty = tid / 16, tx = tid % 16;
    float acc[4][4] = {};
    for (int k0 = 0; k0 < XDIM; k0 += BK) {
        #pragma unroll
        for (int i = 0; i < 4; ++i) {
            int e = tid + i * 256;
            int r = e >> 4, cc = e & 15;
            As[r][cc] = X[(long)(bm + r) * XDIM + k0 + cc];
            Bs[r][cc] = Wih[(long)(bn + r) * XDIM + k0 + cc];
        }
        __syncthreads();
        #pragma unroll
        for (int kk = 0; kk < BK; ++kk) {
            float a[4], b[4];
            #pragma unroll
            for (int i = 0; i < 4; ++i) a[i] = As[ty * 4 + i][kk];
            #pragma unroll
            for (int j = 0; j < 4; ++j) b[j] = Bs[tx * 4 + j][kk];
            #pragma unroll
            for (int i = 0; i < 4; ++i)
                #pragma unroll
                for (int j = 0; j < 4; ++j) acc[i][j] += a[i] * b[j];
        }
        __syncthreads();
    }
    #pragma unroll
    for (int i = 0; i < 4; ++i) {
        int m = bm + ty * 4 + i;
        #pragma unroll
        for (int j = 0; j < 4; ++j) {
            int g = bn + tx * 4 + j;
            int unit = g & 511, gate = g >> 9;
            XP4[((long)m * WHD + unit) * 4 + gate] = acc[i][j] + wb[g];
        }
    }
}

// ---------------- Kernel C: sequential word LSTM, single-XCD L2 dataflow ----------------
// 32 active WGs (blockIdx % 8 == 0 of a 256-block grid -> all on one XCD under the
// round-robin blockIdx->XCD mapping). Role coverage is by blockIdx, so correctness
// never depends on placement. Each WG = 576 threads (9 waves):
//   wave 0  : dedicated poller. Polls h[t-1] row with sc0 loads (L1-bypass, served
//             by the XCD-shared L2, ~200cy) and broadcasts through LDS. Sticky
//             timeout fallback to agent-scope (sc1/LLC) loads guarantees progress
//             even if the placement heuristic is wrong.
//   waves 1-8: 16 units x 32 lanes. Lane p of unit ug owns h-pairs {64i+2p,+1}.
// Producers double-store h+2.0: sc0 (updates local L2 for the fast path) then sc1
// (write-through to LLC so cross-XCD readers / later kernels always see it).
// xp prefetch is issued BEFORE the h-store each step, so the counted vmcnt(2)
// drains exactly the xp load while leaving the 2 stores in flight (vmcnt is
// in-order, everything older than xp gets drained too -> always safe).
// Sentinel protocol unchanged: HS pre-zeroed, value = h+2.0 in [1,3], ready <=> >0.5.
__global__ void __launch_bounds__(576) word_lstm_kernel(
    const float* __restrict__ Whh,  // [2048, 512]
    const float* __restrict__ XP4,  // [N, 512, 4] gate-interleaved
    float*       HS)                // [N, 512]; stores h+2.0; pre-zeroed
{
    if (blockIdx.x & 7) return;          // keep one block per 8 -> one XCD (heuristic)
    const int role = blockIdx.x >> 3;    // 0..31
    const int tid  = threadIdx.x;
    __shared__ float hbuf[WHD];          // h[t-1], offset removed

    if (tid < 64) {
        // ---------------- wave 0: poller / broadcaster ----------------
        const int l = tid;
        bool slow = false;               // sticky fallback to agent-scope polling
        for (int t = 0; t < N_WORDS; ++t) {
            if (t > 0) {
                const unsigned long long* hrow =
                    (const unsigned long long*)(HS + (long)(t - 1) * WHD);
                const unsigned long long* p0 = hrow + l;
                const unsigned long long* p1 = hrow + 64 + l;
                const unsigned long long* p2 = hrow + 128 + l;
                const unsigned long long* p3 = hrow + 192 + l;
                unsigned long long q0, q1, q2, q3;
                float lo0, lo1, lo2, lo3, hi0, hi1, hi2, hi3;
                int spin = 0;
                for (;;) {
                    if (!slow) {
                        asm volatile(
                            "global_load_dwordx2 %0, %4, off sc0\n\t"
                            "global_load_dwordx2 %1, %5, off sc0\n\t"
                            "global_load_dwordx2 %2, %6, off sc0\n\t"
                            "global_load_dwordx2 %3, %7, off sc0\n\t"
                            "s_waitcnt vmcnt(0)"
                            : "=&v"(q0), "=&v"(q1), "=&v"(q2), "=&v"(q3)
                            : "v"(p0), "v"(p1), "v"(p2), "v"(p3)
                            : "memory");
                    } else {
                        q0 = __hip_atomic_load(p0, __ATOMIC_RELAXED, __HIP_MEMORY_SCOPE_AGENT);
                        q1 = __hip_atomic_load(p1, __ATOMIC_RELAXED, __HIP_MEMORY_SCOPE_AGENT);
                        q2 = __hip_atomic_load(p2, __ATOMIC_RELAXED, __HIP_MEMORY_SCOPE_AGENT);
                        q3 = __hip_atomic_load(p3, __ATOMIC_RELAXED, __HIP_MEMORY_SCOPE_AGENT);
                    }
                    lo0 = __uint_as_float((unsigned)q0); hi0 = __uint_as_float((unsigned)(q0 >> 32));
                    lo1 = __uint_as_float((unsigned)q1); hi1 = __uint_as_float((unsigned)(q1 >> 32));
                    lo2 = __uint_as_float((unsigned)q2); hi2 = __uint_as_float((unsigned)(q2 >> 32));
                    lo3 = __uint_as_float((unsigned)q3); hi3 = __uint_as_float((unsigned)(q3 >> 32));
                    float mn = fminf(fminf(fminf(lo0, hi0), fminf(lo1, hi1)),
                                     fminf(fminf(lo2, hi2), fminf(lo3, hi3)));
                    if (mn > 0.5f) break;
                    if (++spin >= 512) slow = true;   // one-time ~60us worst case, then sticky
                }
                float2* hb = (float2*)hbuf;
                hb[l]       = make_float2(lo0 - 2.0f, hi0 - 2.0f);
                hb[l + 64]  = make_float2(lo1 - 2.0f, hi1 - 2.0f);
                hb[l + 128] = make_float2(lo2 - 2.0f, hi2 - 2.0f);
                hb[l + 192] = make_float2(lo3 - 2.0f, hi3 - 2.0f);
            }
            __syncthreads();
        }
        return;
    }

    // ---------------- waves 1-8: compute ----------------
    const int ct = tid - 64;             // 0..511
    const int ug = ct >> 5;              // 0..15 unit-in-wg
    const int p  = ct & 31;              // K-part within unit
    const int j  = role * 16 + ug;       // hidden unit 0..511

    // weights for the paired strided K-set (float2 loads, 8B aligned)
    float w[4][16];
    #pragma unroll
    for (int r = 0; r < 4; ++r) {
        const float* src = Whh + (long)(r * 512 + j) * WHD + 2 * p;
        #pragma unroll
        for (int i = 0; i < 8; ++i) {
            float2 v = *(const float2*)(src + 64 * i);
            w[r][2 * i]     = v.x;
            w[r][2 * i + 1] = v.y;
        }
    }

    float c = 0.0f;
    float h16[16];
    #pragma unroll
    for (int kk = 0; kk < 16; ++kk) h16[kk] = 0.0f;

    float4 xp = *(const float4*)(XP4 + (long)j * 4);   // t=0, compiler-managed wait
    float4 xpn;

    for (int t = 0; t < N_WORDS; ++t) {
        __syncthreads();                 // hbuf now holds h[t-1] (wave 0 wrote pre-barrier)
        if (t > 0) {
            const float2* hb = (const float2*)hbuf;
            #pragma unroll
            for (int k = 0; k < 8; ++k) {
                float2 v = hb[32 * k + p];     // ds_read_b64, 2-way (free) banking
                h16[2 * k]     = v.x;
                h16[2 * k + 1] = v.y;
            }
        }

        float di = 0, df = 0, dg = 0, dq = 0;
        #pragma unroll
        for (int kk = 0; kk < 16; ++kk) {
            di = fmaf(w[0][kk], h16[kk], di);
            df = fmaf(w[1][kk], h16[kk], df);
            dg = fmaf(w[2][kk], h16[kk], dg);
            dq = fmaf(w[3][kk], h16[kk], dq);
        }
        // reduce across the 32 lanes of this unit (xor masks <32 stay in each half)
        #pragma unroll
        for (int m = 16; m >= 1; m >>= 1) {
            di += __shfl_xor(di, m);
            df += __shfl_xor(df, m);
            dg += __shfl_xor(dg, m);
            dq += __shfl_xor(dq, m);
        }

        if (t > 0) {
            // drain exactly the xp prefetch (oldest); the 2 stores from step t-1
            // are newer and may stay in flight. sched_barrier pins the VALU uses
            // of xpn below the wait (rule #18).
            asm volatile("s_waitcnt vmcnt(2)" ::: "memory");
            __builtin_amdgcn_sched_barrier(0);
            xp = xpn;
        }
        if (t + 1 < N_WORDS) {
            const float* xa = XP4 + ((long)(t + 1) * WHD + j) * 4;
            asm volatile("global_load_dwordx4 %0, %1, off"
                         : "=&v"(xpn) : "v"(xa) : "memory");
        }

        float ig = fast_sigmoid(xp.x + di);
        float fg = fast_sigmoid(xp.y + df);
        float gg = fast_tanh(xp.z + dg);
        float og = fast_sigmoid(xp.w + dq);
        c = fg * c + ig * gg;
        float hn = og * fast_tanh(c);

        if (p == 0) {
            float  hv = hn + 2.0f;
            float* hp = HS + (long)t * WHD + j;
            // sc0: update this XCD's L2 (fast same-XCD path); sc1: write-through
            // to LLC (cross-XCD safety + visibility for the logits kernel).
            asm volatile("global_store_dword %0, %1, off sc0\n\t"
                         "global_store_dword %0, %1, off sc1"
                         :: "v"(hp), "v"(hv) : "memory");
        }
        // no trailing barrier: wave 0 overwrites hbuf for t+1 only after the FULL
        // row t is visible, which requires this WG's stores, which are data-dependent
        // on this step's LDS reads -> reads already consumed.
    }
}

// ---------------- Kernel D0: transpose out_W to [512][64] for coalesced reads ----------------
__global__ void __launch_bounds__(256) transpose_outw_kernel(
    const float* __restrict__ outW, float* __restrict__ outWT)
{
    int e = blockIdx.x * 256 + threadIdx.x;  // TAG*WHD
    if (e >= TAG * WHD) return;
    int g = e >> 9, k = e & 511;
    outWT[k * TAG + g] = outW[e];
}

// ---------------- Kernel D: logits + log_softmax, one wave per word ----------------
// HS holds h+2.0 -> subtract the offset inline.
__global__ void __launch_bounds__(64) logits_kernel(
    const float* __restrict__ HS,
    const float* __restrict__ outWT,   // [512][64]
    const float* __restrict__ outb,    // [64]
    float*       __restrict__ out)     // [N, 64]
{
    int n = blockIdx.x;
    int g = threadIdx.x;
    const float* hrow = HS + (long)n * WHD;
    float acc = outb[g];
    #pragma unroll 8
    for (int k = 0; k < WHD; ++k) acc += (hrow[k] - 2.0f) * outWT[k * TAG + g];
    float m = acc;
    #pragma unroll
    for (int s = 32; s >= 1; s >>= 1) m = fmaxf(m, __shfl_xor(m, s));
    float ex = __expf(acc - m);
    float ssum = ex;
    #pragma unroll
    for (int s = 32; s >= 1; s >>= 1) ssum += __shfl_xor(ssum, s);
    out[(long)n * TAG + g] = acc - m - logf(ssum);
}

extern "C" void kernel_launch(void* const* d_in, const int* in_sizes, int n_in,
                              void* d_out, int out_size, void* d_ws, size_t ws_size,
                              hipStream_t stream)
{
    const int*   words = (const int*)   d_in[0];
    const int*   chars = (const int*)   d_in[1];
    const int*   lens  = (const int*)   d_in[2];
    const float* wemb  = (const float*) d_in[3];
    const float* cemb  = (const float*) d_in[4];
    const float* cWih  = (const float*) d_in[5];
    const float* cWhh  = (const float*) d_in[6];
    const float* cb    = (const float*) d_in[7];
    const float* wWih  = (const float*) d_in[8];
    const float* wWhh  = (const float*) d_in[9];
    const float* wb    = (const float*) d_in[10];
    const float* outW  = (const float*) d_in[11];
    const float* outb  = (const float*) d_in[12];
    float* out = (float*)d_out;

    // workspace layout (bytes)
    char* ws = (char*)d_ws;
    size_t off = 0;
    float* h_char = (float*)(ws + off); off += (size_t)N_WORDS * CHD * 4;      // 196,608
    float* X      = (float*)(ws + off); off += (size_t)N_WORDS * XDIM * 4;     // 16.8 MB
    float* XP4    = (float*)(ws + off); off += (size_t)N_WORDS * G4 * 4;       // 67.1 MB
    float* HS     = (float*)(ws + off); off += (size_t)N_WORDS * WHD * 4;      // 16.8 MB
    float* outWT  = (float*)(ws + off); off += (size_t)WHD * TAG * 4;          // 128 KB

    // HS must be zero so the sentinel protocol (stored h+2 > 0.5) is well-defined.
    hipMemsetAsync(HS, 0, (size_t)N_WORDS * WHD * sizeof(float), stream);

    char_lstm_kernel<<<N_WORDS / 256, 256, 0, stream>>>(chars, lens, cemb, cWih, cWhh, cb, h_char);
    build_x_kernel<<<(N_WORDS * XDIM) / 256, 256, 0, stream>>>(words, wemb, h_char, X);
    xp_gemm_kernel<<<(N_WORDS / BM) * (G4 / BN), 256, 0, stream>>>(X, wWih, wb, XP4);
    transpose_outw_kernel<<<(TAG * WHD) / 256, 256, 0, stream>>>(outW, outWT);
    word_lstm_kernel<<<256, 576, 0, stream>>>(wWhh, XP4, HS);
    logits_kernel<<<N_WORDS, 64, 0, stream>>>(HS, outWT, outb, out);
}

// Round 4
// 20004.874 us; speedup vs baseline: 2.7814x; 2.7814x over previous
//
#include <hip/hip_runtime.h>
#include <hip/hip_bf16.h>
#include <math.h>

#define N_WORDS 8192
#define LMAX    16
#define WED     506
#define WHD     512
#define CED     6
#define CHD     6
#define CVOC    128
#define TAG     64
#define XDIM    512      // WED + CHD
#define G4      2048     // 4*WHD
#define NWG     64       // workgroups for the word LSTM

__device__ __forceinline__ float fast_sigmoid(float x) { return 1.0f / (1.0f + __expf(-x)); }
__device__ __forceinline__ float fast_tanh(float x)    { return 2.0f / (1.0f + __expf(-2.0f * x)) - 1.0f; }

__device__ __forceinline__ float q_lo(unsigned long long q) {
    return __uint_as_float((unsigned)(q & 0xffffffffu));
}
__device__ __forceinline__ float q_hi(unsigned long long q) {
    return __uint_as_float((unsigned)(q >> 32));
}
__device__ __forceinline__ bool q_rdy(unsigned long long q0, unsigned long long q1,
                                      unsigned long long q2, unsigned long long q3) {
    float m = fminf(fminf(fminf(q_lo(q0), q_hi(q0)), fminf(q_lo(q1), q_hi(q1))),
                    fminf(fminf(q_lo(q2), q_hi(q2)), fminf(q_lo(q3), q_hi(q3))));
    return m > 0.5f;
}

// ---------------- Kernel A: char-level LSTM, one thread per word ----------------
__global__ void __launch_bounds__(256) char_lstm_kernel(
    const int*   __restrict__ chars,     // [N, LMAX]
    const int*   __restrict__ lens,      // [N]
    const float* __restrict__ char_emb,  // [CVOC, CED]
    const float* __restrict__ cWih,      // [24, 6]
    const float* __restrict__ cWhh,      // [24, 6]
    const float* __restrict__ cb,        // [24]
    float*       __restrict__ h_char)    // [N, CHD]
{
    __shared__ float sWih[24][6], sWhh[24][6], sb[24], semb[CVOC][CED];
    int t = threadIdx.x;
    if (t < 144) { sWih[t / 6][t % 6] = cWih[t]; sWhh[t / 6][t % 6] = cWhh[t]; }
    if (t < 24) sb[t] = cb[t];
    for (int i = t; i < CVOC * CED; i += 256) semb[i / CED][i % CED] = char_emb[i];
    __syncthreads();

    int n = blockIdx.x * 256 + t;
    if (n >= N_WORDS) return;
    int len = lens[n];
    float h[CHD] = {0, 0, 0, 0, 0, 0};
    float c[CHD] = {0, 0, 0, 0, 0, 0};
    for (int l = 0; l < LMAX; ++l) {
        if (l >= len) break;  // once l >= len no further state updates occur
        int ch = chars[n * LMAX + l];
        float e[CED];
        #pragma unroll
        for (int k = 0; k < CED; ++k) e[k] = semb[ch][k];
        float pre[24];
        #pragma unroll
        for (int g = 0; g < 24; ++g) {
            float a = sb[g];
            #pragma unroll
            for (int k = 0; k < CED; ++k) a += e[k] * sWih[g][k];
            #pragma unroll
            for (int k = 0; k < CHD; ++k) a += h[k] * sWhh[g][k];
            pre[g] = a;
        }
        #pragma unroll
        for (int u = 0; u < CHD; ++u) {
            float ig = fast_sigmoid(pre[u]);
            float fg = fast_sigmoid(pre[6 + u]);
            float gg = fast_tanh(pre[12 + u]);
            float og = fast_sigmoid(pre[18 + u]);
            float cn = fg * c[u] + ig * gg;
            c[u] = cn;
            h[u] = og * fast_tanh(cn);
        }
    }
    for (int u = 0; u < CHD; ++u) h_char[n * CHD + u] = h[u];
}

// ---------------- Kernel B0: X = [word_emb gather | h_char] ----------------
__global__ void __launch_bounds__(256) build_x_kernel(
    const int*   __restrict__ words,
    const float* __restrict__ word_emb,  // [WV, WED]
    const float* __restrict__ h_char,    // [N, CHD]
    float*       __restrict__ X)         // [N, XDIM]
{
    long idx = (long)blockIdx.x * 256 + threadIdx.x;
    if (idx >= (long)N_WORDS * XDIM) return;
    int n = (int)(idx >> 9), k = (int)(idx & 511);
    float v;
    if (k < WED) v = word_emb[(long)words[n] * WED + k];
    else         v = h_char[n * CHD + (k - WED)];
    X[idx] = v;
}

// ---------------- Kernel B1: XP4 = X @ Wih^T + b, fp32 tiled GEMM ----------------
// Epilogue writes gate-interleaved layout XP4[t][unit][gate] so the word LSTM
// reads one float4 per thread per step.
#define BM 64
#define BN 64
#define BK 16
__global__ void __launch_bounds__(256) xp_gemm_kernel(
    const float* __restrict__ X,    // [N, 512]
    const float* __restrict__ Wih,  // [2048, 512]
    const float* __restrict__ wb,   // [2048]
    float*       __restrict__ XP4)  // [N, 512, 4]
{
    __shared__ float As[BM][BK + 1];
    __shared__ float Bs[BN][BK + 1];
    int tid = threadIdx.x;
    int bm = (blockIdx.x % (N_WORDS / BM)) * BM;
    int bn = (blockIdx.x / (N_WORDS / BM)) * BN;
    int ty = tid / 16, tx = tid % 16;
    float acc[4][4] = {};
    for (int k0 = 0; k0 < XDIM; k0 += BK) {
        #pragma unroll
        for (int i = 0; i < 4; ++i) {
            int e = tid + i * 256;
            int r = e >> 4, cc = e & 15;
            As[r][cc] = X[(long)(bm + r) * XDIM + k0 + cc];
            Bs[r][cc] = Wih[(long)(bn + r) * XDIM + k0 + cc];
        }
        __syncthreads();
        #pragma unroll
        for (int kk = 0; kk < BK; ++kk) {
            float a[4], b[4];
            #pragma unroll
            for (int i = 0; i < 4; ++i) a[i] = As[ty * 4 + i][kk];
            #pragma unroll
            for (int j = 0; j < 4; ++j) b[j] = Bs[tx * 4 + j][kk];
            #pragma unroll
            for (int i = 0; i < 4; ++i)
                #pragma unroll
                for (int j = 0; j < 4; ++j) acc[i][j] += a[i] * b[j];
        }
        __syncthreads();
    }
    #pragma unroll
    for (int i = 0; i < 4; ++i) {
        int m = bm + ty * 4 + i;
        #pragma unroll
        for (int j = 0; j < 4; ++j) {
            int g = bn + tx * 4 + j;
            int unit = g & 511, gate = g >> 9;
            XP4[((long)m * WHD + unit) * 4 + gate] = acc[i][j] + wb[g];
        }
    }
}

// ---------------- Kernel C: sequential word LSTM (R0 topology, refined sync) -------
// 64 WGs x 256 threads. WG wg owns units [wg*8, wg*8+8); lane p of unit ug owns the
// strided K-set {p + 32*kk}. Sentinel protocol: HS[t][u] written once as h+2.0
// (in [1,3]); HS pre-zeroed; ready <=> v > 0.5.
// Changes vs the 18.06ms baseline (R0):
//  (1) 2-deep pipelined poll (C++, compiler-managed waits): rounds A and B alternate
//      with an initial ~256cy s_sleep stagger, halving the effective sampling period.
//  (2) raw s_barrier with lgkmcnt-only wait replaces __syncthreads: no per-step
//      vmcnt(0) drain, so each wave's h-store ack and xp prefetch stay in flight
//      across the barrier and retire under the next step's poll.
__global__ void __launch_bounds__(256, 1) word_lstm_kernel(
    const float* __restrict__ Whh,  // [2048, 512]
    const float* __restrict__ XP4,  // [N, 512, 4] gate-interleaved
    float*       HS)                // [N, 512]; stores h+2.0; pre-zeroed
{
    __shared__ float hbuf[WHD];     // h[t-1] (offset removed)

    const int tid = threadIdx.x;
    const int wg  = blockIdx.x;      // 0..63
    const int ug  = tid >> 5;        // 0..7 unit-in-block
    const int p   = tid & 31;        // K-part within unit
    const int j   = wg * 8 + ug;     // hidden unit 0..511

    // weights for the strided K-set
    float w[4][16];
    #pragma unroll
    for (int r = 0; r < 4; ++r) {
        const float* src = Whh + (long)(r * 512 + j) * WHD + p;
        #pragma unroll
        for (int kk = 0; kk < 16; ++kk) w[r][kk] = src[kk * 32];
    }

    float c = 0.0f;
    float h16[16];
    #pragma unroll
    for (int kk = 0; kk < 16; ++kk) h16[kk] = 0.0f;

    for (int t = 0; t < N_WORDS; ++t) {
        // xp load depends only on t -> issue before the poll so HBM latency hides
        const float4 xp = *(const float4*)(XP4 + ((long)t * WHD + j) * 4);

        if (t > 0) {
            if (tid < 64) {
                const unsigned long long* hrow =
                    (const unsigned long long*)(HS + (long)(t - 1) * WHD);
                #define LDQ(i) __hip_atomic_load(&hrow[(i) * 64 + tid], \
                                __ATOMIC_RELAXED, __HIP_MEMORY_SCOPE_AGENT)
                unsigned long long a0, a1, a2, a3, b0, b1, b2, b3;
                unsigned long long q0, q1, q2, q3;
                // round A in flight, ~256cy stagger, round B in flight
                a0 = LDQ(0); a1 = LDQ(1); a2 = LDQ(2); a3 = LDQ(3);
                asm volatile("s_sleep 4");
                b0 = LDQ(0); b1 = LDQ(1); b2 = LDQ(2); b3 = LDQ(3);
                for (;;) {
                    if (q_rdy(a0, a1, a2, a3)) { q0 = a0; q1 = a1; q2 = a2; q3 = a3; break; }
                    a0 = LDQ(0); a1 = LDQ(1); a2 = LDQ(2); a3 = LDQ(3);
                    if (q_rdy(b0, b1, b2, b3)) { q0 = b0; q1 = b1; q2 = b2; q3 = b3; break; }
                    b0 = LDQ(0); b1 = LDQ(1); b2 = LDQ(2); b3 = LDQ(3);
                }
                #undef LDQ
                hbuf[2 * tid]       = q_lo(q0) - 2.0f;
                hbuf[2 * tid + 1]   = q_hi(q0) - 2.0f;
                hbuf[128 + 2 * tid] = q_lo(q1) - 2.0f;
                hbuf[129 + 2 * tid] = q_hi(q1) - 2.0f;
                hbuf[256 + 2 * tid] = q_lo(q2) - 2.0f;
                hbuf[257 + 2 * tid] = q_hi(q2) - 2.0f;
                hbuf[384 + 2 * tid] = q_lo(q3) - 2.0f;
                hbuf[385 + 2 * tid] = q_hi(q3) - 2.0f;
            }
            // raw barrier: LDS ordering only (writer's ds_writes drained by lgkmcnt),
            // NO vmcnt drain — h-store acks and xp prefetch stay in flight.
            asm volatile("s_waitcnt lgkmcnt(0)" ::: "memory");
            __builtin_amdgcn_s_barrier();
            asm volatile("" ::: "memory");
            #pragma unroll
            for (int kk = 0; kk < 16; ++kk) h16[kk] = hbuf[p + 32 * kk];
        }

        float di = 0, df = 0, dg = 0, dq = 0;
        #pragma unroll
        for (int kk = 0; kk < 16; ++kk) {
            di = fmaf(w[0][kk], h16[kk], di);
            df = fmaf(w[1][kk], h16[kk], df);
            dg = fmaf(w[2][kk], h16[kk], dg);
            dq = fmaf(w[3][kk], h16[kk], dq);
        }
        // reduce over the 32 lanes of this unit (xor masks <32 stay in each half-wave)
        #pragma unroll
        for (int m = 16; m >= 1; m >>= 1) {
            di += __shfl_xor(di, m);
            df += __shfl_xor(df, m);
            dg += __shfl_xor(dg, m);
            dq += __shfl_xor(dq, m);
        }
        float ig = fast_sigmoid(xp.x + di);
        float fg = fast_sigmoid(xp.y + df);
        float gg = fast_tanh(xp.z + dg);
        float og = fast_sigmoid(xp.w + dq);
        c = fg * c + ig * gg;
        float hn = og * fast_tanh(c);

        if (p == 0)
            __hip_atomic_store(&HS[(long)t * WHD + j], hn + 2.0f, __ATOMIC_RELAXED,
                               __HIP_MEMORY_SCOPE_AGENT);
        // NOTE: no trailing barrier needed. Wave 0 only overwrites hbuf for step t+1
        // after ALL 512 h[t] values are globally visible, which implies every wave
        // (including ours) has already consumed its step-t LDS reads.
    }
}

// ---------------- Kernel D0: transpose out_W to [512][64] for coalesced reads ----------------
__global__ void __launch_bounds__(256) transpose_outw_kernel(
    const float* __restrict__ outW, float* __restrict__ outWT)
{
    int e = blockIdx.x * 256 + threadIdx.x;  // TAG*WHD
    if (e >= TAG * WHD) return;
    int g = e >> 9, k = e & 511;
    outWT[k * TAG + g] = outW[e];
}

// ---------------- Kernel D: logits + log_softmax, one wave per word ----------------
// HS holds h+2.0 -> subtract the offset inline.
__global__ void __launch_bounds__(64) logits_kernel(
    const float* __restrict__ HS,
    const float* __restrict__ outWT,   // [512][64]
    const float* __restrict__ outb,    // [64]
    float*       __restrict__ out)     // [N, 64]
{
    int n = blockIdx.x;
    int g = threadIdx.x;
    const float* hrow = HS + (long)n * WHD;
    float acc = outb[g];
    #pragma unroll 8
    for (int k = 0; k < WHD; ++k) acc += (hrow[k] - 2.0f) * outWT[k * TAG + g];
    float m = acc;
    #pragma unroll
    for (int s = 32; s >= 1; s >>= 1) m = fmaxf(m, __shfl_xor(m, s));
    float ex = __expf(acc - m);
    float ssum = ex;
    #pragma unroll
    for (int s = 32; s >= 1; s >>= 1) ssum += __shfl_xor(ssum, s);
    out[(long)n * TAG + g] = acc - m - logf(ssum);
}

extern "C" void kernel_launch(void* const* d_in, const int* in_sizes, int n_in,
                              void* d_out, int out_size, void* d_ws, size_t ws_size,
                              hipStream_t stream)
{
    const int*   words = (const int*)   d_in[0];
    const int*   chars = (const int*)   d_in[1];
    const int*   lens  = (const int*)   d_in[2];
    const float* wemb  = (const float*) d_in[3];
    const float* cemb  = (const float*) d_in[4];
    const float* cWih  = (const float*) d_in[5];
    const float* cWhh  = (const float*) d_in[6];
    const float* cb    = (const float*) d_in[7];
    const float* wWih  = (const float*) d_in[8];
    const float* wWhh  = (const float*) d_in[9];
    const float* wb    = (const float*) d_in[10];
    const float* outW  = (const float*) d_in[11];
    const float* outb  = (const float*) d_in[12];
    float* out = (float*)d_out;

    // workspace layout (bytes)
    char* ws = (char*)d_ws;
    size_t off = 0;
    float* h_char = (float*)(ws + off); off += (size_t)N_WORDS * CHD * 4;      // 196,608
    float* X      = (float*)(ws + off); off += (size_t)N_WORDS * XDIM * 4;     // 16.8 MB
    float* XP4    = (float*)(ws + off); off += (size_t)N_WORDS * G4 * 4;       // 67.1 MB
    float* HS     = (float*)(ws + off); off += (size_t)N_WORDS * WHD * 4;      // 16.8 MB
    float* outWT  = (float*)(ws + off); off += (size_t)WHD * TAG * 4;          // 128 KB

    // HS must be zero so the sentinel protocol (stored h+2 > 0.5) is well-defined.
    hipMemsetAsync(HS, 0, (size_t)N_WORDS * WHD * sizeof(float), stream);

    char_lstm_kernel<<<N_WORDS / 256, 256, 0, stream>>>(chars, lens, cemb, cWih, cWhh, cb, h_char);
    build_x_kernel<<<(N_WORDS * XDIM) / 256, 256, 0, stream>>>(words, wemb, h_char, X);
    xp_gemm_kernel<<<(N_WORDS / BM) * (G4 / BN), 256, 0, stream>>>(X, wWih, wb, XP4);
    transpose_outw_kernel<<<(TAG * WHD) / 256, 256, 0, stream>>>(outW, outWT);
    word_lstm_kernel<<<NWG, 256, 0, stream>>>(wWhh, XP4, HS);
    logits_kernel<<<N_WORDS, 64, 0, stream>>>(HS, outWT, outb, out);
}